// Round 4
// baseline (145.108 us; speedup 1.0000x reference)
//
#include <hip/hip_runtime.h>

#define CROPPX 4
#define H 504
#define W 504
#define IMG 512
#define NB 16
#define NCH 3
#define KS 11
#define RAD 5
#define TW 64               // output cols per wave
#define STRIP (TW + 2*RAD)  // 74 input cols per wave
#define RPS 21              // output rows per wave-segment
#define WPB 4               // waves per block
#define BROWS (RPS * WPB)   // 84 output rows per block
#define NYB 6               // 6 * 84 = 504 exactly
#define NXT 8               // ceil(504/64): last tile has 56 valid cols
#define TOTAL (RPS + 2*RAD) // 31 row ingests per wave

__global__ __launch_bounds__(256, 4) void ssim_main(const float* __restrict__ img1,
                                                    const float* __restrict__ img2,
                                                    float* __restrict__ partial) {
    const int lane = threadIdx.x & 63;
    const int wv   = threadIdx.x >> 6;
    const int gx0  = blockIdx.x * TW;                  // first output col
    const int y0   = blockIdx.y * BROWS + wv * RPS;    // first output row (this wave)
    const int b    = blockIdx.z;

    // wave-private row buffers: a wave only reads LDS it wrote -> NO barriers
    __shared__ float2 rowBuf[WPB][STRIP];
    float2* const myRow = rowBuf[wv];

    const float* p1 = img1 + (size_t)(b * NCH) * IMG * IMG + (size_t)CROPPX * IMG + CROPPX;
    const float* p2 = img2 + (size_t)(b * NCH) * IMG * IMG + (size_t)CROPPX * IMG + CROPPX;

    // branch-free column addressing: clamp + mask
    const int  c0   = gx0 - RAD + lane;                 // strip col (first 64)
    const int  c0c  = min(max(c0, 0), W - 1);
    const bool c0ok = (unsigned)c0 < (unsigned)W;
    const int  c1   = c0 + 64;                          // strip col (10 lanes)
    const int  c1c  = min(c1, W - 1);
    const bool c1ok = (unsigned)c1 < (unsigned)W;
    const bool lane2 = lane < (STRIP - 64);

    // register-resident history ring: 11 rows x 5 stats (compile-time indices)
    float r1[KS], r2[KS], r11[KS], r22[KS], r12[KS];
    #pragma unroll
    for (int j = 0; j < KS; ++j) { r1[j]=0.f; r2[j]=0.f; r11[j]=0.f; r22[j]=0.f; r12[j]=0.f; }

    float vs1 = 0.f, vs2 = 0.f, vs11 = 0.f, vs22 = 0.f, vs12 = 0.f;
    float ssum = 0.f;
    const float C1 = 6.5025f, C2 = 58.5225f;
    const float inv121 = 1.0f / 121.0f;
    const bool colValid = (gx0 + lane) < W;

    // prefetch row for iter = 0 (clamped row address, masked result)
    float a0, b0, a1 = 0.f, b1 = 0.f;
    {
        const int r  = y0 - RAD;
        const int rc = min(max(r, 0), H - 1);
        const bool rok = (unsigned)r < (unsigned)H;
        const size_t ro = (size_t)rc * IMG;
        const float ta0 = p1[ro + c0c], tb0 = p2[ro + c0c];
        a0 = (rok && c0ok) ? ta0 : 0.f;
        b0 = (rok && c0ok) ? tb0 : 0.f;
        if (lane2) {
            const float ta1 = p1[ro + c1c], tb1 = p2[ro + c1c];
            a1 = (rok && c1ok) ? ta1 : 0.f;
            b1 = (rok && c1ok) ? tb1 : 0.f;
        }
    }

    for (int base = 0; base < TOTAL; base += KS) {      // base in {0,11,22}; base%11==0
        #pragma unroll
        for (int j = 0; j < KS; ++j) {
            const int iter = base + j;
            if (iter >= TOTAL) break;

            // publish staged row to this wave's private LDS row (no barrier needed)
            myRow[lane] = make_float2(a0, b0);
            if (lane2) myRow[64 + lane] = make_float2(a1, b1);

            // prefetch next row (overlaps the compute below)
            if (iter + 1 < TOTAL) {
                const int r  = y0 - RAD + iter + 1;
                const int rc = min(max(r, 0), H - 1);
                const bool rok = (unsigned)r < (unsigned)H;
                const size_t ro = (size_t)rc * IMG;
                const float ta0 = p1[ro + c0c], tb0 = p2[ro + c0c];
                a0 = (rok && c0ok) ? ta0 : 0.f;
                b0 = (rok && c0ok) ? tb0 : 0.f;
                if (lane2) {
                    const float ta1 = p1[ro + c1c], tb1 = p2[ro + c1c];
                    a1 = (rok && c1ok) ? ta1 : 0.f;
                    b1 = (rok && c1ok) ? tb1 : 0.f;
                }
            }

            // horizontal 11-tap sums for output col gx0+lane
            float h1 = 0.f, h2 = 0.f, h11 = 0.f, h22 = 0.f, h12 = 0.f;
            #pragma unroll
            for (int dx = 0; dx < KS; ++dx) {
                const float2 ab = myRow[lane + dx];
                h1 += ab.x;
                h2 += ab.y;
                h11 = fmaf(ab.x, ab.x, h11);
                h22 = fmaf(ab.y, ab.y, h22);
                h12 = fmaf(ab.x, ab.y, h12);
            }

            // vertical sliding window; ring slot == iter % 11 == j
            vs1  += h1  - r1[j];  r1[j]  = h1;
            vs2  += h2  - r2[j];  r2[j]  = h2;
            vs11 += h11 - r11[j]; r11[j] = h11;
            vs22 += h22 - r22[j]; r22[j] = h22;
            vs12 += h12 - r12[j]; r12[j] = h12;

            // window covers rows [iter-10, iter] => output row iter-5 of segment
            if (iter >= 2 * RAD && colValid) {
                const float mu1 = vs1 * inv121;
                const float mu2 = vs2 * inv121;
                const float mu1s = mu1 * mu1;
                const float mu2s = mu2 * mu2;
                const float m12  = mu1 * mu2;
                const float s1  = fmaf(vs11, inv121, -mu1s);
                const float s2  = fmaf(vs22, inv121, -mu2s);
                const float s12 = fmaf(vs12, inv121, -m12);
                const float num = (2.0f * m12 + C1) * (2.0f * s12 + C2);
                const float den = (mu1s + mu2s + C1) * (s1 + s2 + C2);
                ssum = fmaf(num, __builtin_amdgcn_rcpf(den), ssum);
            }
        }
    }

    // wave (64-lane) reduction of ssum
    for (int off = 32; off > 0; off >>= 1)
        ssum += __shfl_down(ssum, off);
    if (lane == 0) {
        const int bidx = (((blockIdx.z * gridDim.y + blockIdx.y) * gridDim.x + blockIdx.x) * WPB) + wv;
        partial[bidx] = ssum;
    }
}

__global__ __launch_bounds__(256) void ssim_final(const float* __restrict__ partial,
                                                  int n, float* __restrict__ out) {
    __shared__ double sh[256];
    double s = 0.0;
    for (int i = threadIdx.x; i < n; i += 256) s += (double)partial[i];
    sh[threadIdx.x] = s;
    __syncthreads();
    for (int stride = 128; stride > 0; stride >>= 1) {
        if (threadIdx.x < stride) sh[threadIdx.x] += sh[threadIdx.x + stride];
        __syncthreads();
    }
    if (threadIdx.x == 0)
        out[0] = (float)(sh[0] / ((double)NB * (double)H * (double)W));
}

extern "C" void kernel_launch(void* const* d_in, const int* in_sizes, int n_in,
                              void* d_out, int out_size, void* d_ws, size_t ws_size,
                              hipStream_t stream) {
    const float* img1 = (const float*)d_in[0];
    const float* img2 = (const float*)d_in[1];
    float* out = (float*)d_out;
    float* partial = (float*)d_ws;  // NXT*NYB*NB*WPB floats = 12 KiB

    dim3 grid(NXT, NYB, NB);
    ssim_main<<<grid, 256, 0, stream>>>(img1, img2, partial);
    ssim_final<<<1, 256, 0, stream>>>(partial, NXT * NYB * NB * WPB, out);
}